// Round 5
// baseline (4423.219 us; speedup 1.0000x reference)
//
#include <hip/hip_runtime.h>
#include <math.h>

#define N_NODES 200000
#define H_CH    128
#define GRP     64          // channel group width (2 groups of 64)
#define NNZ_E   3200000
#define K_DEG   15

// bucketed CSR build parameters
#define EPB     4096        // edges per block in bucket pass A
#define BSHIFT  9           // 512 rows per bucket
#define BROWS   512
#define NBUCK   391         // ceil(200000 / 512)
#define BCAP    9216        // per-bucket staging capacity (mean 8192, +11 sigma)

// ---------- softmax over 16 logits ----------
__global__ void softmax_k(const float* __restrict__ logits, float* __restrict__ w) {
    if (threadIdx.x == 0) {
        float m = -1e30f;
        for (int i = 0; i <= K_DEG; ++i) m = fmaxf(m, logits[i]);
        float e[K_DEG + 1];
        float s = 0.f;
        for (int i = 0; i <= K_DEG; ++i) { e[i] = expf(logits[i] - m); s += e[i]; }
        float inv = 1.0f / s;
        for (int i = 0; i <= K_DEG; ++i) w[i] = e[i] * inv;
    }
}

// ---------- bucket pass A: block-local LDS binning by row bucket ----------
__global__ __launch_bounds__(256) void bucketA_k(
    const int* __restrict__ row, const int* __restrict__ col,
    const float* __restrict__ vals,
    int* __restrict__ gfill, uint2* __restrict__ stag, int nnz) {
    __shared__ int cnt[NBUCK];
    __shared__ int excl[NBUCK];
    __shared__ int gbase[NBUCK];
    __shared__ int sm[256];
    __shared__ uint2 sstag[EPB];
    __shared__ unsigned short sb[EPB];

    int tid = threadIdx.x;
    int base = blockIdx.x * EPB;

    for (int t = tid; t < NBUCK; t += 256) cnt[t] = 0;
    __syncthreads();

    int r[16], c[16], b[16];
    float v[16];
#pragma unroll
    for (int j = 0; j < 16; ++j) {
        int i = base + j * 256 + tid;
        if (i < nnz) {
            r[j] = row[i]; c[j] = col[i]; v[j] = vals[i];
            b[j] = r[j] >> BSHIFT;
            atomicAdd(&cnt[b[j]], 1);
        } else {
            b[j] = -1;
        }
    }
    __syncthreads();

    {
        int b0 = 2 * tid, b1 = 2 * tid + 1;
        int c0 = (b0 < NBUCK) ? cnt[b0] : 0;
        int c1 = (b1 < NBUCK) ? cnt[b1] : 0;
        int pair = c0 + c1;
        sm[tid] = pair;
        __syncthreads();
        int incl = pair;
        for (int off = 1; off < 256; off <<= 1) {
            int tv = (tid >= off) ? sm[tid - off] : 0;
            __syncthreads();
            incl += tv;
            sm[tid] = incl;
            __syncthreads();
        }
        int pexcl = incl - pair;
        if (b0 < NBUCK) excl[b0] = pexcl;
        if (b1 < NBUCK) excl[b1] = pexcl + c0;
    }
    __syncthreads();

    for (int t = tid; t < NBUCK; t += 256) {
        int cb = cnt[t];
        gbase[t] = (cb > 0) ? atomicAdd(&gfill[t], cb) : 0;
    }
    __syncthreads();
    for (int t = tid; t < NBUCK; t += 256) cnt[t] = excl[t];
    __syncthreads();

#pragma unroll
    for (int j = 0; j < 16; ++j) {
        if (b[j] >= 0) {
            int p = atomicAdd(&cnt[b[j]], 1);
            sstag[p] = make_uint2(((unsigned)(r[j] & 511) << 18) | (unsigned)c[j],
                                  __float_as_uint(v[j]));
            sb[p] = (unsigned short)b[j];
        }
    }
    __syncthreads();

    int tot = nnz - base; if (tot > EPB) tot = EPB;
    for (int i = tid; i < tot; i += 256) {
        int bb = sb[i];
        size_t gp = (size_t)bb * BCAP + gbase[bb] + (i - excl[bb]);
        stag[gp] = sstag[i];
    }
}

// ---------- tiny scan over 391 bucket totals ----------
__global__ void scanG_k(const int* __restrict__ gfill, int* __restrict__ bbase,
                        int* __restrict__ row_ptr) {
    __shared__ int sm[256];
    int tid = threadIdx.x;
    int j0 = 2 * tid, j1 = 2 * tid + 1;
    int c0 = (j0 < NBUCK) ? gfill[j0] : 0;
    int c1 = (j1 < NBUCK) ? gfill[j1] : 0;
    int pair = c0 + c1;
    sm[tid] = pair;
    __syncthreads();
    int incl = pair;
    for (int off = 1; off < 256; off <<= 1) {
        int t = (tid >= off) ? sm[tid - off] : 0;
        __syncthreads();
        incl += t;
        sm[tid] = incl;
        __syncthreads();
    }
    int pexcl = incl - pair;
    if (j0 < NBUCK) bbase[j0] = pexcl;
    if (j1 < NBUCK) bbase[j1] = pexcl + c0;
    if (tid == 0) row_ptr[N_NODES] = NNZ_E;
}

// ---------- bucket pass B: bucket-local CSR build ----------
__global__ __launch_bounds__(256) void bucketB_k(
    const uint2* __restrict__ stag, const int* __restrict__ gfill,
    const int* __restrict__ bbase, int* __restrict__ row_ptr,
    int2* __restrict__ csr) {
    __shared__ int hist[BROWS];
    __shared__ int lexcl[BROWS];
    __shared__ int sm[256];
    int b = blockIdx.x;
    int n = gfill[b];
    int cs = bbase[b];
    const uint2* s = stag + (size_t)b * BCAP;
    int tid = threadIdx.x;

    hist[tid] = 0; hist[tid + 256] = 0;
    __syncthreads();
    for (int i = tid; i < n; i += 256)
        atomicAdd(&hist[s[i].x >> 18], 1);
    __syncthreads();

    int j0 = 2 * tid, j1 = 2 * tid + 1;
    int c0 = hist[j0], c1 = hist[j1];
    int pair = c0 + c1;
    sm[tid] = pair;
    __syncthreads();
    int incl = pair;
    for (int off = 1; off < 256; off <<= 1) {
        int t = (tid >= off) ? sm[tid - off] : 0;
        __syncthreads();
        incl += t;
        sm[tid] = incl;
        __syncthreads();
    }
    int pexcl = incl - pair;
    lexcl[j0] = pexcl;
    lexcl[j1] = pexcl + c0;

    int rbase = b << BSHIFT;
    if (rbase + j0 < N_NODES) row_ptr[rbase + j0] = cs + lexcl[j0];
    if (rbase + j1 < N_NODES) row_ptr[rbase + j1] = cs + lexcl[j1];
    hist[j0] = lexcl[j0];
    hist[j1] = lexcl[j1];
    __syncthreads();

    for (int i = tid; i < n; i += 256) {
        uint2 e = s[i];
        int rl = (int)(e.x >> 18);
        int p = cs + atomicAdd(&hist[rl], 1);
        int2 cv;
        cv.x = (int)(e.x & 0x3FFFF);
        cv.y = (int)e.y;
        csr[p] = cv;
    }
}

// ================= combined-group kernels (XCD-split) =================
// One dispatch covers BOTH 64-ch groups. Blocks with (blockIdx%8)<4 (XCDs
// 0-3 under the measured round-robin block->XCD mapping, m09) take group 0;
// the rest take group 1. Each group's T-lines are then fetched by only 4
// XCDs' L2s instead of ~7 -> gather fetch replication ~4/6.8 of Round-4.
// T layout: [r][128] interleaved; group g = columns [64g, 64g+64) = lines
// 4g..4g+3 of each 512B row, so the two groups touch disjoint cache lines.
// Mapping is a perf heuristic only: any block->XCD mapping stays correct.

__global__ __launch_bounds__(512) void firstC_k(
    const int* __restrict__ rp, const int2* __restrict__ csr,
    const float* __restrict__ x, float* __restrict__ T1, float* __restrict__ out,
    const float* __restrict__ w, const float* __restrict__ alpha_p) {
    int bid = blockIdx.x;
    int pos = (bid >> 3) * 4 + (bid & 3);           // per-group block index
    int wid = pos * 8 + (threadIdx.x >> 6);
    int r = __builtin_amdgcn_readfirstlane(wid);
    if (r >= N_NODES) return;
    int g = (bid >> 2) & 1;                          // XCD half -> channel group
    int ch = (g << 6) | (threadIdx.x & 63);
    const float* base = x + ch;                      // gather x[c*128 + ch]
    int e0 = rp[r], e1 = rp[r + 1];
    float a0 = 0.f, a1 = 0.f, a2 = 0.f, a3 = 0.f;
    float a4 = 0.f, a5 = 0.f, a6 = 0.f, a7 = 0.f;
    int e = e0;
    for (; e + 8 <= e1; e += 8) {
        int2 cv0 = csr[e],     cv1 = csr[e + 1], cv2 = csr[e + 2], cv3 = csr[e + 3];
        int2 cv4 = csr[e + 4], cv5 = csr[e + 5], cv6 = csr[e + 6], cv7 = csr[e + 7];
        a0 = fmaf(__int_as_float(cv0.y), base[(unsigned)cv0.x * H_CH], a0);
        a1 = fmaf(__int_as_float(cv1.y), base[(unsigned)cv1.x * H_CH], a1);
        a2 = fmaf(__int_as_float(cv2.y), base[(unsigned)cv2.x * H_CH], a2);
        a3 = fmaf(__int_as_float(cv3.y), base[(unsigned)cv3.x * H_CH], a3);
        a4 = fmaf(__int_as_float(cv4.y), base[(unsigned)cv4.x * H_CH], a4);
        a5 = fmaf(__int_as_float(cv5.y), base[(unsigned)cv5.x * H_CH], a5);
        a6 = fmaf(__int_as_float(cv6.y), base[(unsigned)cv6.x * H_CH], a6);
        a7 = fmaf(__int_as_float(cv7.y), base[(unsigned)cv7.x * H_CH], a7);
    }
    for (; e + 4 <= e1; e += 4) {
        int2 cv0 = csr[e], cv1 = csr[e + 1], cv2 = csr[e + 2], cv3 = csr[e + 3];
        a0 = fmaf(__int_as_float(cv0.y), base[(unsigned)cv0.x * H_CH], a0);
        a1 = fmaf(__int_as_float(cv1.y), base[(unsigned)cv1.x * H_CH], a1);
        a2 = fmaf(__int_as_float(cv2.y), base[(unsigned)cv2.x * H_CH], a2);
        a3 = fmaf(__int_as_float(cv3.y), base[(unsigned)cv3.x * H_CH], a3);
    }
    for (; e < e1; ++e) {
        int2 cv = csr[e];
        a0 = fmaf(__int_as_float(cv.y), base[(unsigned)cv.x * H_CH], a0);
    }
    float s = ((a0 + a1) + (a2 + a3)) + ((a4 + a5) + (a6 + a7));
    size_t idx = (size_t)r * H_CH + ch;
    float xr = x[idx];
    float w0 = w[0], w1 = w[1], al = alpha_p[0];
    float t1 = s - xr;
    float o = -(w0 * xr + w1 * t1) + al * (xr - 0.5f * s);
    T1[idx] = t1;
    out[idx] = o;
}

__global__ __launch_bounds__(512) void chebC_k(
    const int* __restrict__ rp, const int2* __restrict__ csr,
    const float* __restrict__ Tcur, const float* __restrict__ Tprev,
    float* __restrict__ Tnext, float* __restrict__ out,
    const float* __restrict__ w, int k) {
    int bid = blockIdx.x;
    int pos = (bid >> 3) * 4 + (bid & 3);
    int wid = pos * 8 + (threadIdx.x >> 6);
    int r = __builtin_amdgcn_readfirstlane(wid);
    if (r >= N_NODES) return;
    int g = (bid >> 2) & 1;
    int ch = (g << 6) | (threadIdx.x & 63);
    const float* base = Tcur + ch;                   // gather Tcur[c*128 + ch]
    int e0 = rp[r], e1 = rp[r + 1];
    float a0 = 0.f, a1 = 0.f, a2 = 0.f, a3 = 0.f;
    float a4 = 0.f, a5 = 0.f, a6 = 0.f, a7 = 0.f;
    int e = e0;
    for (; e + 8 <= e1; e += 8) {
        int2 cv0 = csr[e],     cv1 = csr[e + 1], cv2 = csr[e + 2], cv3 = csr[e + 3];
        int2 cv4 = csr[e + 4], cv5 = csr[e + 5], cv6 = csr[e + 6], cv7 = csr[e + 7];
        a0 = fmaf(__int_as_float(cv0.y), base[(unsigned)cv0.x * H_CH], a0);
        a1 = fmaf(__int_as_float(cv1.y), base[(unsigned)cv1.x * H_CH], a1);
        a2 = fmaf(__int_as_float(cv2.y), base[(unsigned)cv2.x * H_CH], a2);
        a3 = fmaf(__int_as_float(cv3.y), base[(unsigned)cv3.x * H_CH], a3);
        a4 = fmaf(__int_as_float(cv4.y), base[(unsigned)cv4.x * H_CH], a4);
        a5 = fmaf(__int_as_float(cv5.y), base[(unsigned)cv5.x * H_CH], a5);
        a6 = fmaf(__int_as_float(cv6.y), base[(unsigned)cv6.x * H_CH], a6);
        a7 = fmaf(__int_as_float(cv7.y), base[(unsigned)cv7.x * H_CH], a7);
    }
    for (; e + 4 <= e1; e += 4) {
        int2 cv0 = csr[e], cv1 = csr[e + 1], cv2 = csr[e + 2], cv3 = csr[e + 3];
        a0 = fmaf(__int_as_float(cv0.y), base[(unsigned)cv0.x * H_CH], a0);
        a1 = fmaf(__int_as_float(cv1.y), base[(unsigned)cv1.x * H_CH], a1);
        a2 = fmaf(__int_as_float(cv2.y), base[(unsigned)cv2.x * H_CH], a2);
        a3 = fmaf(__int_as_float(cv3.y), base[(unsigned)cv3.x * H_CH], a3);
    }
    for (; e < e1; ++e) {
        int2 cv = csr[e];
        a0 = fmaf(__int_as_float(cv.y), base[(unsigned)cv.x * H_CH], a0);
    }
    float s = ((a0 + a1) + (a2 + a3)) + ((a4 + a5) + (a6 + a7));
    size_t idx = (size_t)r * H_CH + ch;
    float tc = Tcur[idx];
    float tp = Tprev[idx];            // k>=3: aliases Tnext; own-thread read-before-write
    float wk = w[k];
    float tn = 2.0f * (s - tc) - tp;
    float o = out[idx];
    o -= wk * tn;
    out[idx] = o;
    Tnext[idx] = tn;
}

// ================= fallback per-group kernels (Round-4 verified) =================
__global__ __launch_bounds__(512) void first_k(
    const int* __restrict__ rp, const int2* __restrict__ csr,
    const float* __restrict__ x, float* __restrict__ T1g, float* __restrict__ out,
    const float* __restrict__ w, const float* __restrict__ alpha_p, int goff) {
    int wid = blockIdx.x * 8 + (threadIdx.x >> 6);
    int r = __builtin_amdgcn_readfirstlane(wid);
    if (r >= N_NODES) return;
    int lane = threadIdx.x & 63;
    const float* base = x + goff + lane;
    int e0 = rp[r], e1 = rp[r + 1];
    float a0 = 0.f, a1 = 0.f, a2 = 0.f, a3 = 0.f;
    int e = e0;
    for (; e + 4 <= e1; e += 4) {
        int2 cv0 = csr[e], cv1 = csr[e + 1], cv2 = csr[e + 2], cv3 = csr[e + 3];
        a0 = fmaf(__int_as_float(cv0.y), base[(unsigned)cv0.x * H_CH], a0);
        a1 = fmaf(__int_as_float(cv1.y), base[(unsigned)cv1.x * H_CH], a1);
        a2 = fmaf(__int_as_float(cv2.y), base[(unsigned)cv2.x * H_CH], a2);
        a3 = fmaf(__int_as_float(cv3.y), base[(unsigned)cv3.x * H_CH], a3);
    }
    for (; e < e1; ++e) {
        int2 cv = csr[e];
        a0 = fmaf(__int_as_float(cv.y), base[(unsigned)cv.x * H_CH], a0);
    }
    float s = (a0 + a1) + (a2 + a3);
    size_t idxg = (size_t)r * GRP + lane;
    size_t idxf = (size_t)r * H_CH + goff + lane;
    float xr = x[idxf];
    float w0 = w[0], w1 = w[1], al = alpha_p[0];
    float t1 = s - xr;
    float o = -(w0 * xr + w1 * t1) + al * (xr - 0.5f * s);
    T1g[idxg] = t1;
    out[idxf] = o;
}

__global__ __launch_bounds__(512) void cheb_k(
    const int* __restrict__ rp, const int2* __restrict__ csr,
    const float* __restrict__ Tcur, const float* TprevBase, int tprevStride,
    float* Tnext, float* __restrict__ out,
    const float* __restrict__ w, int k, int goff) {
    int wid = blockIdx.x * 8 + (threadIdx.x >> 6);
    int r = __builtin_amdgcn_readfirstlane(wid);
    if (r >= N_NODES) return;
    int lane = threadIdx.x & 63;
    const float* base = Tcur + lane;
    int e0 = rp[r], e1 = rp[r + 1];
    float a0 = 0.f, a1 = 0.f, a2 = 0.f, a3 = 0.f;
    int e = e0;
    for (; e + 4 <= e1; e += 4) {
        int2 cv0 = csr[e], cv1 = csr[e + 1], cv2 = csr[e + 2], cv3 = csr[e + 3];
        a0 = fmaf(__int_as_float(cv0.y), base[(unsigned)cv0.x * GRP], a0);
        a1 = fmaf(__int_as_float(cv1.y), base[(unsigned)cv1.x * GRP], a1);
        a2 = fmaf(__int_as_float(cv2.y), base[(unsigned)cv2.x * GRP], a2);
        a3 = fmaf(__int_as_float(cv3.y), base[(unsigned)cv3.x * GRP], a3);
    }
    for (; e < e1; ++e) {
        int2 cv = csr[e];
        a0 = fmaf(__int_as_float(cv.y), base[(unsigned)cv.x * GRP], a0);
    }
    float s = (a0 + a1) + (a2 + a3);
    size_t idxg = (size_t)r * GRP + lane;
    size_t idxf = (size_t)r * H_CH + goff + lane;
    float tc = Tcur[idxg];
    float tp = TprevBase[(size_t)r * tprevStride + lane];
    float wk = w[k];
    float tn = 2.0f * (s - tc) - tp;
    float o = out[idxf];
    o -= wk * tn;
    out[idxf] = o;
    Tnext[idxg] = tn;
}

extern "C" void kernel_launch(void* const* d_in, const int* in_sizes, int n_in,
                              void* d_out, int out_size, void* d_ws, size_t ws_size,
                              hipStream_t stream) {
    const float* x      = (const float*)d_in[0];
    const float* vals   = (const float*)d_in[1];
    const float* logits = (const float*)d_in[2];
    const float* alpha  = (const float*)d_in[3];
    const int*   erow   = (const int*)d_in[4];
    const int*   ecol   = (const int*)d_in[5];
    float* out = (float*)d_out;

    const size_t NG  = (size_t)N_NODES * GRP;      // per-group elements
    const size_t NF  = (size_t)N_NODES * H_CH;     // full-width elements
    // combined layout: bufA/bufB are N x 128 (both groups interleaved)
    const size_t REQ_COMBINED =
        (2 * NF + 0) * sizeof(float) + (size_t)NNZ_E * sizeof(int2) +
        (N_NODES + 1 + 2 * NBUCK + 64) * sizeof(int);
    bool combined = ws_size >= REQ_COMBINED;

    const size_t TSZ = combined ? NF : NG;
    float* bufA    = (float*)d_ws;                 // stag aliases bufA (build phase only)
    float* bufB    = bufA + TSZ;
    int2*  csr     = (int2*)(bufB + TSZ);
    uint2* stag    = (uint2*)bufA;                 // 28.8 MB <= bufA size (51.2/102.4 MB)
    int*   row_ptr = (int*)(csr + NNZ_E);          // N+1
    int*   gfill   = row_ptr + (N_NODES + 1);      // NBUCK
    int*   bbase   = gfill + NBUCK;                // NBUCK
    float* w_buf   = (float*)(bbase + NBUCK);      // 16

    hipMemsetAsync(gfill, 0, NBUCK * sizeof(int), stream);
    softmax_k<<<1, 64, 0, stream>>>(logits, w_buf);

    int nblkA = (NNZ_E + EPB - 1) / EPB;
    bucketA_k<<<nblkA, 256, 0, stream>>>(erow, ecol, vals, gfill, stag, NNZ_E);
    scanG_k<<<1, 256, 0, stream>>>(gfill, bbase, row_ptr);
    bucketB_k<<<NBUCK, 256, 0, stream>>>(stag, gfill, bbase, row_ptr, csr);
    // build phase done: stag (aliased on bufA) is dead; bufA first written at k=2

    if (combined) {
        int gridC = 2 * ((N_NODES + 7) / 8);       // 50000 blocks, XCD-split groups
        firstC_k<<<gridC, 512, 0, stream>>>(row_ptr, csr, x, bufB, out, w_buf, alpha);
        // k = 2: Tprev = x (same [r][128] layout)
        chebC_k<<<gridC, 512, 0, stream>>>(row_ptr, csr, bufB, x, bufA, out, w_buf, 2);
        float* Tcur = bufA;
        float* Tprev = bufB;
        for (int k = 3; k <= K_DEG; ++k) {
            chebC_k<<<gridC, 512, 0, stream>>>(row_ptr, csr, Tcur, Tprev, Tprev,
                                               out, w_buf, k);
            float* t = Tcur; Tcur = Tprev; Tprev = t;
        }
    } else {
        int grid = (N_NODES + 7) / 8;
        for (int g = 0; g < H_CH / GRP; ++g) {
            int goff = g * GRP;
            first_k<<<grid, 512, 0, stream>>>(row_ptr, csr, x, bufB, out, w_buf, alpha, goff);
            cheb_k<<<grid, 512, 0, stream>>>(row_ptr, csr, bufB, x + goff, H_CH, bufA,
                                             out, w_buf, 2, goff);
            float* Tcur = bufA;
            float* Tprev = bufB;
            for (int k = 3; k <= K_DEG; ++k) {
                cheb_k<<<grid, 512, 0, stream>>>(row_ptr, csr, Tcur, Tprev, GRP, Tprev,
                                                 out, w_buf, k, goff);
                float* t = Tcur; Tcur = Tprev; Tprev = t;
            }
        }
    }
}